// Round 2
// baseline (379.570 us; speedup 1.0000x reference)
//
#include <hip/hip_runtime.h>

// HEALPix pad, p=1, n=128, C=128, B12=24 (B=2 x 12 faces), fp32.
// out[b12, c, r, col] (130x130) from in[b12, c, 128, 128] + neighbor-face halos.
// R4: output-linear streaming. One block per plane writes the whole padded
// plane (borders included) as 4225 dense 16B-aligned float4 stores; interior
// sources come as 4 scalar dword gathers (L1-coalesced). No partial-line RMW,
// no cross-block line sharing, no nontemporal hints.

#define NPLANE_OUT 16900   // 130*130 = 4225 * 4  -> whole plane is aligned quads

__device__ __forceinline__ float hp_face(const float* __restrict__ in, size_t baseoff,
                                         int q, int i, int j) {
  return in[baseoff + ((size_t)q << 21) + (i << 7) + j];
}

__device__ __forceinline__ float hp_val(const float* __restrict__ in, size_t baseoff,
                                        int type, int m, int face, int r, int col) {
  const int L = 127;
  if (r == 0) {
    if (col == 0) {  // TL corner
      if (type == 0) return hp_face(in, baseoff, (m + 2) & 3, 0, 0);
      if (type == 1) return 0.5f * (hp_face(in, baseoff, m, L, 0) +
                                    hp_face(in, baseoff, (m + 3) & 3, 0, L));
      return hp_face(in, baseoff, m, L, L);
    }
    if (col == 129) {  // TR corner
      if (type == 0) return hp_face(in, baseoff, (m + 1) & 3, L, 0);
      if (type == 1) return hp_face(in, baseoff, 4 + ((m + 1) & 3), L, 0);
      return hp_face(in, baseoff, 8 + ((m + 1) & 3), L, 0);
    }
    int j = col - 1;  // top row
    if (type == 0) return hp_face(in, baseoff, (m + 1) & 3, j, 0);
    if (type == 1) return hp_face(in, baseoff, m, L, j);
    return hp_face(in, baseoff, 4 + ((m + 1) & 3), L, j);
  }
  if (r == 129) {
    if (col == 0) {  // BL corner
      if (type == 0) return hp_face(in, baseoff, (m + 3) & 3, 0, L);
      if (type == 1) return hp_face(in, baseoff, 4 + ((m + 3) & 3), 0, L);
      return hp_face(in, baseoff, 8 + ((m + 3) & 3), 0, L);
    }
    if (col == 129) {  // BR corner
      if (type == 0) return hp_face(in, baseoff, 8 + m, 0, 0);
      if (type == 1) return 0.5f * (hp_face(in, baseoff, 8 + ((m + 3) & 3), 0, L) +
                                    hp_face(in, baseoff, 8 + m, L, 0));
      return hp_face(in, baseoff, 8 + ((m + 2) & 3), L, L);
    }
    int j = col - 1;  // bottom row
    if (type == 0) return hp_face(in, baseoff, 4 + m, 0, j);
    if (type == 1) return hp_face(in, baseoff, 8 + ((m + 3) & 3), 0, j);
    return hp_face(in, baseoff, 8 + ((m + 3) & 3), j, L);
  }
  int i = r - 1;
  if (col == 0) {  // left column
    if (type == 0) return hp_face(in, baseoff, (m + 3) & 3, 0, i);
    if (type == 1) return hp_face(in, baseoff, (m + 3) & 3, i, L);
    return hp_face(in, baseoff, 4 + m, i, L);
  }
  // col == 129, right column
  if (type == 0) return hp_face(in, baseoff, 4 + ((m + 1) & 3), i, 0);
  if (type == 1) return hp_face(in, baseoff, 8 + m, i, 0);
  return hp_face(in, baseoff, 8 + ((m + 1) & 3), L, i);
}

typedef float f4v __attribute__((ext_vector_type(4)));

__global__ __launch_bounds__(256) void CREDITHEALPix_90975997264316_kernel(
    const float* __restrict__ in, float* __restrict__ out) {
  int plane = blockIdx.x;      // 0..3071 : b12*128 + c
  int b12 = plane >> 7;
  int c = plane & 127;
  int batch = (b12 >= 12) ? 1 : 0;
  int face = b12 - batch * 12;
  int type = face >> 2;        // 0=north, 1=equatorial, 2=south
  int m = face & 3;
  size_t baseoff = (((size_t)batch * 1536) + (size_t)c) << 14;  // (batch*12*128+c)*16384
  const float* __restrict__ src = in + baseoff + ((size_t)face << 21);
  float* __restrict__ oplane = out + (size_t)plane * NPLANE_OUT;

  // Whole plane = 4225 16B-aligned output quads; stream them in order.
  for (int t4 = threadIdx.x; t4 < 4225; t4 += 256) {
    int e = t4 << 2;             // flat output index of quad start
    int r = e / 130;             // compiler magic-div
    int col = e - r * 130;
    f4v v;
    if (r >= 1 && r <= 128 && col >= 1 && col <= 125) {
      // fast path: all 4 elems strictly interior, same row
      const float* __restrict__ p = src + ((r - 1) << 7) + (col - 1);
      v[0] = p[0];
      v[1] = p[1];
      v[2] = p[2];
      v[3] = p[3];
    } else {
      // slow path: per-element (handles borders and row-crossing quads)
      #pragma unroll
      for (int k = 0; k < 4; ++k) {
        int ek = e + k;
        int rk = ek / 130;
        int ck = ek - rk * 130;
        if (rk == 0 || rk == 129 || ck == 0 || ck == 129) {
          v[k] = hp_val(in, baseoff, type, m, face, rk, ck);
        } else {
          v[k] = src[((rk - 1) << 7) + (ck - 1)];
        }
      }
    }
    *(f4v*)(oplane + e) = v;     // dense, 16B-aligned dwordx4 store
  }
}

extern "C" void kernel_launch(void* const* d_in, const int* in_sizes, int n_in,
                              void* d_out, int out_size, void* d_ws, size_t ws_size,
                              hipStream_t stream) {
  const float* in = (const float*)d_in[0];
  float* out = (float*)d_out;
  // one block per plane; each block writes its whole 130x130 plane densely
  dim3 grid(3072, 1, 1);
  dim3 block(256, 1, 1);
  CREDITHEALPix_90975997264316_kernel<<<grid, block, 0, stream>>>(in, out);
}

// Round 3
// 344.598 us; speedup vs baseline: 1.1015x; 1.1015x over previous
//
#include <hip/hip_runtime.h>

// HEALPix pad, p=1, n=128, C=128, B12=24 (B=2 x 12 faces), fp32.
// out[b12, c, r, col] (130x130) from in[b12, c, 128, 128] + neighbor-face halos.
// R5: table-driven gather. Kernel1 builds a (face, e) -> input-index table
// (12 x 16900 int32 = 811KB, L2-resident) in d_ws. Kernel2 streams the whole
// output as dense 16B-aligned float4 stores, branch-free: per quad = 1 int4
// table load + 4 scalar gathers + 1 float4 store, 4 quads/thread batched for
// MLP. Kernel3 patches the 2048 averaged corners (equatorial TL/BR).
// Host fallback to the R4 monolithic kernel if ws is too small.

#define NPLANE_OUT 16900   // 130*130 = 4225 quads, 16B-aligned
#define TAB_ELEMS  (12 * NPLANE_OUT)

__device__ __forceinline__ int hp_fidx(int q, int i, int j) {
  return (q << 21) + (i << 7) + j;   // face, row, col -> flat offset within (batch,c) cube
}

// index-producing mirror of hp_val; the two averaged corners (equatorial TL/BR)
// return one of their two sources and are patched by hp_patch_corners.
__device__ int hp_idx(int type, int m, int face, int r, int col) {
  const int L = 127;
  if (r == 0) {
    if (col == 0) {  // TL corner
      if (type == 0) return hp_fidx((m + 2) & 3, 0, 0);
      if (type == 1) return hp_fidx(m, L, 0);            // avg corner: patched later
      return hp_fidx(m, L, L);
    }
    if (col == 129) {  // TR corner
      if (type == 0) return hp_fidx((m + 1) & 3, L, 0);
      if (type == 1) return hp_fidx(4 + ((m + 1) & 3), L, 0);
      return hp_fidx(8 + ((m + 1) & 3), L, 0);
    }
    int j = col - 1;  // top row
    if (type == 0) return hp_fidx((m + 1) & 3, j, 0);
    if (type == 1) return hp_fidx(m, L, j);
    return hp_fidx(4 + ((m + 1) & 3), L, j);
  }
  if (r == 129) {
    if (col == 0) {  // BL corner
      if (type == 0) return hp_fidx((m + 3) & 3, 0, L);
      if (type == 1) return hp_fidx(4 + ((m + 3) & 3), 0, L);
      return hp_fidx(8 + ((m + 3) & 3), 0, L);
    }
    if (col == 129) {  // BR corner
      if (type == 0) return hp_fidx(8 + m, 0, 0);
      if (type == 1) return hp_fidx(8 + ((m + 3) & 3), 0, L);  // avg corner: patched later
      return hp_fidx(8 + ((m + 2) & 3), L, L);
    }
    int j = col - 1;  // bottom row
    if (type == 0) return hp_fidx(4 + m, 0, j);
    if (type == 1) return hp_fidx(8 + ((m + 3) & 3), 0, j);
    return hp_fidx(8 + ((m + 3) & 3), j, L);
  }
  int i = r - 1;
  if (col == 0) {  // left column
    if (type == 0) return hp_fidx((m + 3) & 3, 0, i);
    if (type == 1) return hp_fidx((m + 3) & 3, i, L);
    return hp_fidx(4 + m, i, L);
  }
  if (col == 129) {  // right column
    if (type == 0) return hp_fidx(4 + ((m + 1) & 3), i, 0);
    if (type == 1) return hp_fidx(8 + m, i, 0);
    return hp_fidx(8 + ((m + 1) & 3), L, i);
  }
  // interior
  return (face << 21) + ((r - 1) << 7) + (col - 1);
}

__global__ __launch_bounds__(256) void hp_build_table(int* __restrict__ tab) {
  int idx = blockIdx.x * 256 + threadIdx.x;
  if (idx >= TAB_ELEMS) return;
  int face = idx / NPLANE_OUT;
  int e = idx - face * NPLANE_OUT;
  int r = e / 130;
  int col = e - r * 130;
  tab[idx] = hp_idx(face >> 2, face & 3, face, r, col);
}

typedef float f4v __attribute__((ext_vector_type(4)));
typedef int   i4v __attribute__((ext_vector_type(4)));

// main streaming gather: 12675 blocks x 256 threads x 4 quads = 12,979,200 quads
__global__ __launch_bounds__(256) void CREDITHEALPix_90975997264316_kernel(
    const float* __restrict__ in, const int* __restrict__ tab,
    float* __restrict__ out) {
  int q0 = blockIdx.x * 1024 + threadIdx.x;

  i4v tq[4];
  size_t inbase[4];
  #pragma unroll
  for (int k = 0; k < 4; ++k) {
    int Q = q0 + (k << 8);
    int plane = Q / 4225;          // magic div (constant)
    int t4 = Q - plane * 4225;
    int b12 = plane >> 7;
    int c = plane & 127;
    int batch = (b12 >= 12) ? 1 : 0;
    int face = b12 - batch * 12;
    inbase[k] = (((size_t)(batch ? 1536 : 0)) + (size_t)c) << 14;
    tq[k] = *(const i4v*)(tab + face * NPLANE_OUT + (t4 << 2));
  }
  f4v v[4];
  #pragma unroll
  for (int k = 0; k < 4; ++k) {
    const float* __restrict__ b = in + inbase[k];
    v[k][0] = b[tq[k][0]];
    v[k][1] = b[tq[k][1]];
    v[k][2] = b[tq[k][2]];
    v[k][3] = b[tq[k][3]];
  }
  #pragma unroll
  for (int k = 0; k < 4; ++k) {
    *(f4v*)(out + ((size_t)(q0 + (k << 8)) << 2)) = v[k];
  }
}

// patch the 2 averaged corners of each equatorial plane (1024 planes x 2)
__global__ __launch_bounds__(256) void hp_patch_corners(
    const float* __restrict__ in, float* __restrict__ out) {
  int t = blockIdx.x * 256 + threadIdx.x;
  if (t >= 2048) return;
  int corner = t & 1;           // 0=TL, 1=BR
  int pl = t >> 1;              // 0..1023
  int batch = (pl >= 512) ? 1 : 0;
  int rem = pl - batch * 512;
  int m = rem >> 7;             // equatorial face = 4+m
  int c = rem & 127;
  int b12 = batch * 12 + 4 + m;
  int plane = (b12 << 7) + c;
  size_t baseoff = (((size_t)batch * 1536) + (size_t)c) << 14;
  float v;
  int e;
  if (corner == 0) {
    v = 0.5f * (in[baseoff + hp_fidx(m, 127, 0)] +
                in[baseoff + hp_fidx((m + 3) & 3, 0, 127)]);
    e = 0;
  } else {
    v = 0.5f * (in[baseoff + hp_fidx(8 + ((m + 3) & 3), 0, 127)] +
                in[baseoff + hp_fidx(8 + m, 127, 0)]);
    e = NPLANE_OUT - 1;
  }
  out[(size_t)plane * NPLANE_OUT + e] = v;
}

// ---------------- R4 fallback (used only if ws too small) ----------------
__device__ __forceinline__ float hp_face(const float* __restrict__ in, size_t baseoff,
                                         int q, int i, int j) {
  return in[baseoff + ((size_t)q << 21) + (i << 7) + j];
}

__device__ float hp_val(const float* __restrict__ in, size_t baseoff,
                        int type, int m, int face, int r, int col) {
  const int L = 127;
  if (r == 0) {
    if (col == 0) {
      if (type == 0) return hp_face(in, baseoff, (m + 2) & 3, 0, 0);
      if (type == 1) return 0.5f * (hp_face(in, baseoff, m, L, 0) +
                                    hp_face(in, baseoff, (m + 3) & 3, 0, L));
      return hp_face(in, baseoff, m, L, L);
    }
    if (col == 129) {
      if (type == 0) return hp_face(in, baseoff, (m + 1) & 3, L, 0);
      if (type == 1) return hp_face(in, baseoff, 4 + ((m + 1) & 3), L, 0);
      return hp_face(in, baseoff, 8 + ((m + 1) & 3), L, 0);
    }
    int j = col - 1;
    if (type == 0) return hp_face(in, baseoff, (m + 1) & 3, j, 0);
    if (type == 1) return hp_face(in, baseoff, m, L, j);
    return hp_face(in, baseoff, 4 + ((m + 1) & 3), L, j);
  }
  if (r == 129) {
    if (col == 0) {
      if (type == 0) return hp_face(in, baseoff, (m + 3) & 3, 0, L);
      if (type == 1) return hp_face(in, baseoff, 4 + ((m + 3) & 3), 0, L);
      return hp_face(in, baseoff, 8 + ((m + 3) & 3), 0, L);
    }
    if (col == 129) {
      if (type == 0) return hp_face(in, baseoff, 8 + m, 0, 0);
      if (type == 1) return 0.5f * (hp_face(in, baseoff, 8 + ((m + 3) & 3), 0, L) +
                                    hp_face(in, baseoff, 8 + m, L, 0));
      return hp_face(in, baseoff, 8 + ((m + 2) & 3), L, L);
    }
    int j = col - 1;
    if (type == 0) return hp_face(in, baseoff, 4 + m, 0, j);
    if (type == 1) return hp_face(in, baseoff, 8 + ((m + 3) & 3), 0, j);
    return hp_face(in, baseoff, 8 + ((m + 3) & 3), j, L);
  }
  int i = r - 1;
  if (col == 0) {
    if (type == 0) return hp_face(in, baseoff, (m + 3) & 3, 0, i);
    if (type == 1) return hp_face(in, baseoff, (m + 3) & 3, i, L);
    return hp_face(in, baseoff, 4 + m, i, L);
  }
  if (type == 0) return hp_face(in, baseoff, 4 + ((m + 1) & 3), i, 0);
  if (type == 1) return hp_face(in, baseoff, 8 + m, i, 0);
  return hp_face(in, baseoff, 8 + ((m + 1) & 3), L, i);
}

__global__ __launch_bounds__(256) void hp_fallback_kernel(
    const float* __restrict__ in, float* __restrict__ out) {
  int plane = blockIdx.x;
  int b12 = plane >> 7;
  int c = plane & 127;
  int batch = (b12 >= 12) ? 1 : 0;
  int face = b12 - batch * 12;
  int type = face >> 2;
  int m = face & 3;
  size_t baseoff = (((size_t)batch * 1536) + (size_t)c) << 14;
  const float* __restrict__ src = in + baseoff + ((size_t)face << 21);
  float* __restrict__ oplane = out + (size_t)plane * NPLANE_OUT;

  for (int t4 = threadIdx.x; t4 < 4225; t4 += 256) {
    int e = t4 << 2;
    int r = e / 130;
    int col = e - r * 130;
    f4v v;
    if (r >= 1 && r <= 128 && col >= 1 && col <= 125) {
      const float* __restrict__ p = src + ((r - 1) << 7) + (col - 1);
      v[0] = p[0]; v[1] = p[1]; v[2] = p[2]; v[3] = p[3];
    } else {
      #pragma unroll
      for (int k = 0; k < 4; ++k) {
        int ek = e + k;
        int rk = ek / 130;
        int ck = ek - rk * 130;
        if (rk == 0 || rk == 129 || ck == 0 || ck == 129) {
          v[k] = hp_val(in, baseoff, type, m, face, rk, ck);
        } else {
          v[k] = src[((rk - 1) << 7) + (ck - 1)];
        }
      }
    }
    *(f4v*)(oplane + e) = v;
  }
}

extern "C" void kernel_launch(void* const* d_in, const int* in_sizes, int n_in,
                              void* d_out, int out_size, void* d_ws, size_t ws_size,
                              hipStream_t stream) {
  const float* in = (const float*)d_in[0];
  float* out = (float*)d_out;
  if (ws_size >= (size_t)TAB_ELEMS * sizeof(int)) {
    int* tab = (int*)d_ws;
    hp_build_table<<<dim3((TAB_ELEMS + 255) / 256), dim3(256), 0, stream>>>(tab);
    // 12675 blocks * 1024 quads = 12,979,200 = 3072 planes * 4225 quads exactly
    CREDITHEALPix_90975997264316_kernel<<<dim3(12675), dim3(256), 0, stream>>>(in, tab, out);
    hp_patch_corners<<<dim3(8), dim3(256), 0, stream>>>(in, out);
  } else {
    hp_fallback_kernel<<<dim3(3072), dim3(256), 0, stream>>>(in, out);
  }
}